// Round 2
// baseline (382.156 us; speedup 1.0000x reference)
//
#include <hip/hip_runtime.h>
#include <hip/hip_bf16.h>
#include <cstddef>

// MoE gate: B,S,D,E,K = 4,4096,2048,64,2. N = 16384 tokens.
// out layout: dispatch [N][E][K] (2,097,152 f) | combine [N][E][K] | lbl | z
namespace {
constexpr int kD = 2048;
constexpr int kE = 64;
constexpr int kN = 16384;
constexpr size_t kDispatchFloats = (size_t)kN * kE * 2;  // 2,097,152
}

// ---------------------------------------------------------------------------
__global__ void zero_ws_kernel(float* __restrict__ ws) {
  ws[threadIdx.x] = 0.0f;  // 256 accumulator slots (129 used)
}

// ---------------------------------------------------------------------------
// Kernel 1: partial logits. Block = (token-tile of 64, d-quarter of 512).
// Grid = 256*4 = 1024 blocks, 256 threads = 4 waves; wave = 16 experts.
// x chunks staged in LDS (double-buffered, XOR-swizzled for b128 reads).
// Partial[dq][token][e] stored inside token's own output slots:
//   dq 0/1 -> dispatch[n*128 + dq*64 + e], dq 2/3 -> combine[n*128 + (dq-2)*64 + e]
__global__ __launch_bounds__(256)
void logits_kernel(const float* __restrict__ x, const float* __restrict__ W,
                   float* __restrict__ out) {
  __shared__ float xs[2][4096];  // 2 x 64 tok x 64 d, 32 KB
  const int tid  = threadIdx.x;
  const int lane = tid & 63;
  const int wv   = __builtin_amdgcn_readfirstlane(tid >> 6);  // expert group
  const int dq   = blockIdx.x & 3;
  const int tile = blockIdx.x >> 2;

  const int tq  = tid >> 4;                 // staging token sub-index
  const int q   = tid & 15;                 // float4 column within 64-d chunk
  const int swq = ((q ^ (tq & 7)) << 2);    // swizzled float offset

  // x as float4: row stride 512; this block covers d range [dq*512, dq*512+512)
  const float4* __restrict__ x4 =
      reinterpret_cast<const float4*>(x) + (size_t)tile * 64 * 512 + dq * 128 + q;
  const float* __restrict__ wb = W + (size_t)(wv * 16) * kD + dq * 512;

  float acc[16];
#pragma unroll
  for (int e = 0; e < 16; ++e) acc[e] = 0.0f;

  float4 st[4];
  // stage chunk 0
#pragma unroll
  for (int k = 0; k < 4; ++k) st[k] = x4[(size_t)(k * 16 + tq) * 512];
#pragma unroll
  for (int k = 0; k < 4; ++k)
    *reinterpret_cast<float4*>(&xs[0][(k * 16 + tq) * 64 + swq]) = st[k];
  __syncthreads();

  int cur = 0;
  for (int c = 0; c < 8; ++c) {
    if (c < 7) {  // issue next chunk's global loads early (latency hides under FMAs)
#pragma unroll
      for (int k = 0; k < 4; ++k)
        st[k] = x4[(size_t)(k * 16 + tq) * 512 + (c + 1) * 16];
    }
    const float* __restrict__ wc = wb + c * 64;
    const float* __restrict__ xr = &xs[cur][lane * 64];
#pragma unroll
    for (int q0 = 0; q0 < 16; q0 += 2) {
      const float4 xa =
          *reinterpret_cast<const float4*>(&xr[(q0 ^ (lane & 7)) << 2]);
      const float4 xb =
          *reinterpret_cast<const float4*>(&xr[((q0 + 1) ^ (lane & 7)) << 2]);
#pragma unroll
      for (int e = 0; e < 16; ++e) {
        const float* __restrict__ w = wc + e * kD + q0 * 4;  // uniform -> s_load
        acc[e] = fmaf(xa.x, w[0], acc[e]);
        acc[e] = fmaf(xa.y, w[1], acc[e]);
        acc[e] = fmaf(xa.z, w[2], acc[e]);
        acc[e] = fmaf(xa.w, w[3], acc[e]);
        acc[e] = fmaf(xb.x, w[4], acc[e]);
        acc[e] = fmaf(xb.y, w[5], acc[e]);
        acc[e] = fmaf(xb.z, w[6], acc[e]);
        acc[e] = fmaf(xb.w, w[7], acc[e]);
      }
    }
    if (c < 7) {  // write next chunk into the other buffer
#pragma unroll
      for (int k = 0; k < 4; ++k)
        *reinterpret_cast<float4*>(&xs[cur ^ 1][(k * 16 + tq) * 64 + swq]) = st[k];
    }
    __syncthreads();
    cur ^= 1;
  }

  // epilogue: write this (dq, wave)'s 16-expert partial into token's own slots
  const size_t n = (size_t)tile * 64 + lane;
  float* __restrict__ dst = out + ((dq < 2) ? (size_t)0 : kDispatchFloats) +
                            n * 128 + (dq & 1) * 64 + wv * 16;
#pragma unroll
  for (int k = 0; k < 4; ++k)
    *reinterpret_cast<float4*>(dst + k * 4) =
        make_float4(acc[4 * k], acc[4 * k + 1], acc[4 * k + 2], acc[4 * k + 3]);
}

// ---------------------------------------------------------------------------
// Kernel 2: sum 4 partials -> logits, softmax, top-2, write outputs, losses.
// 256 blocks x 256 threads, 64 tokens/block. Reads only its own tokens' slots,
// then overwrites them -> no cross-block hazard.
__global__ __launch_bounds__(256)
void gate_kernel(float* __restrict__ out, float* __restrict__ ws) {
  __shared__ float lg[64][65];
  __shared__ int ti0[64], ti1[64];
  __shared__ float tv0[64], tv1[64], tz2[64];
  const int tid  = threadIdx.x;
  const int tile = blockIdx.x;

  float* __restrict__ outd = out + (size_t)tile * 8192;
  float* __restrict__ outc = out + kDispatchFloats + (size_t)tile * 8192;
  const float4* __restrict__ d4 = reinterpret_cast<const float4*>(outd);
  const float4* __restrict__ c4 = reinterpret_cast<const float4*>(outc);

  const int tq = tid >> 4, q = tid & 15;
#pragma unroll
  for (int k = 0; k < 4; ++k) {
    const int t = k * 16 + tq;
    const float4 a = d4[t * 32 + q];
    const float4 b = d4[t * 32 + 16 + q];
    const float4 c = c4[t * 32 + q];
    const float4 d = c4[t * 32 + 16 + q];
    lg[t][q * 4 + 0] = a.x + b.x + c.x + d.x;
    lg[t][q * 4 + 1] = a.y + b.y + c.y + d.y;
    lg[t][q * 4 + 2] = a.z + b.z + c.z + d.z;
    lg[t][q * 4 + 3] = a.w + b.w + c.w + d.w;
  }
  __syncthreads();

  if (tid < 64) {
    float v0 = -INFINITY, v1 = -INFINITY;
    int i0 = 0, i1 = 0;
    for (int e = 0; e < kE; ++e) {
      const float l = lg[tid][e];
      if (l > v0) { v1 = v0; i1 = i0; v0 = l; i0 = e; }
      else if (l > v1) { v1 = l; i1 = e; }
    }
    const float m = v0;
    float s = 0.0f;
    for (int e = 0; e < kE; ++e) s += __expf(lg[tid][e] - m);
    const float rs = 1.0f / s;
    float zexp = 0.0f;
    for (int e = 0; e < kE; ++e) zexp += __expf(__expf(lg[tid][e] - m) * rs);
    const float z = logf(zexp);
    ti0[tid] = i0; ti1[tid] = i1;
    tv0[tid] = rs;                    // exp(v0-m)*rs with v0==m
    tv1[tid] = __expf(v1 - m) * rs;
    tz2[tid] = z * z;
  }
  __syncthreads();

  // losses: thread = expert, deterministic in-block order; 256 atomics/address
  if (tid < kE) {
    float g = 0.0f, cnt = 0.0f;
    for (int t = 0; t < 64; ++t) {
      if (ti0[t] == tid) { g += tv0[t]; cnt += 1.0f; }
      if (ti1[t] == tid) { g += tv1[t]; cnt += 1.0f; }
    }
    atomicAdd(&ws[tid], g);
    atomicAdd(&ws[kE + tid], cnt);
    float z2 = tz2[tid];
    for (int off = 32; off; off >>= 1) z2 += __shfl_down(z2, off);
    if (tid == 0) atomicAdd(&ws[2 * kE], z2);
  }

  // outputs: 4 threads per token, 8 float4 per tensor each (overwrites partials)
  {
    const int t = tid >> 2, sub = tid & 3;
    const int i0 = ti0[t], i1 = ti1[t];
    const float v0 = tv0[t], v1 = tv1[t];
    float4* __restrict__ dp = reinterpret_cast<float4*>(outd) + t * 32;
    float4* __restrict__ cp = reinterpret_cast<float4*>(outc) + t * 32;
#pragma unroll
    for (int j = 0; j < 8; ++j) {
      const int qq = sub * 8 + j;
      const int e0 = qq * 2, e1 = qq * 2 + 1;
      const float d0v = (e0 == i0 || e0 == i1) ? 1.0f : 0.0f;
      const float d1v = (e1 == i0 || e1 == i1) ? 1.0f : 0.0f;
      const float c0 = (e0 == i0) ? v0 : ((e0 == i1) ? v1 : 0.0f);
      const float c1 = (e1 == i0) ? v0 : ((e1 == i1) ? v1 : 0.0f);
      dp[qq] = make_float4(d0v, 0.0f, d1v, 0.0f);
      cp[qq] = make_float4(c0, 0.0f, c1, 0.0f);
    }
  }
}

// ---------------------------------------------------------------------------
__global__ void finalize_kernel(const float* __restrict__ ws,
                                float* __restrict__ out) {
  const int e = threadIdx.x;  // 64 threads
  float prod = ws[e] * ws[kE + e];
  for (int off = 32; off; off >>= 1) prod += __shfl_down(prod, off);
  if (e == 0) {
    const size_t base = kDispatchFloats * 2;
    const float invN = 1.0f / (float)kN;
    out[base]     = prod * ((float)kE * invN * invN);  // load_balancing_loss
    out[base + 1] = ws[2 * kE] * invN;                 // router_z_loss
  }
}

// ---------------------------------------------------------------------------
extern "C" void kernel_launch(void* const* d_in, const int* in_sizes, int n_in,
                              void* d_out, int out_size, void* d_ws,
                              size_t ws_size, hipStream_t stream) {
  const float* x = (const float*)d_in[0];  // [4,4096,2048] fp32
  const float* W = (const float*)d_in[1];  // [64,2048] fp32
  float* out = (float*)d_out;
  float* ws = (float*)d_ws;

  zero_ws_kernel<<<1, 256, 0, stream>>>(ws);
  logits_kernel<<<1024, 256, 0, stream>>>(x, W, out);
  gate_kernel<<<256, 256, 0, stream>>>(out, ws);
  finalize_kernel<<<1, kE, 0, stream>>>(ws, out);
}

// Round 6
// 155.807 us; speedup vs baseline: 2.4528x; 2.4528x over previous
//
#include <hip/hip_runtime.h>
#include <hip/hip_bf16.h>
#include <cstddef>

// MoE gate: B,S,D,E,K = 4,4096,2048,64,2. N = 16384 tokens.
// out layout: dispatch [N][E][K] (2,097,152 f) | combine [N][E][K] | lbl | z
namespace {
constexpr int kD = 2048;
constexpr int kE = 64;
constexpr int kN = 16384;
constexpr size_t kDispatchFloats = (size_t)kN * kE * 2;  // 2,097,152
}

// ---------------------------------------------------------------------------
__global__ void zero_ws_kernel(float* __restrict__ ws) {
  ws[threadIdx.x] = 0.0f;  // 256 accumulator slots (129 used)
}

// ---------------------------------------------------------------------------
// Kernel 1: partial logits. Grid 1024 = 256 token-tiles x 4 d-quarters,
// mapped tile = bid&255, dq = bid>>8 so a tile's 4 blocks share an XCD/L2.
// Block = 256 threads = 4 waves; wave = 16-expert group; lane = token.
// Inner loop: per-lane global float4 x loads (vmcnt only, depth-1 prefetch of
// a 32B pair) + wave-uniform W s_loads (lgkmcnt only) + pure v_fma. No LDS.
// Partial[dq][token][e] stored inside the token's own output slots:
//   dq 0/1 -> dispatch[n*128 + dq*64 + eg*16], dq 2/3 -> combine[...]
__global__ __launch_bounds__(256)
void logits_kernel(const float* __restrict__ x, const float* __restrict__ W,
                   float* __restrict__ out) {
  const int tid  = threadIdx.x;
  const int lane = tid & 63;
  const int wv   = __builtin_amdgcn_readfirstlane(tid >> 6);  // expert group
  const int tile = blockIdx.x & 255;
  const int dq   = blockIdx.x >> 8;

  // x as float4: token row = 512 float4s; this block covers [dq*512, dq*512+512)
  const float4* __restrict__ x4 = reinterpret_cast<const float4*>(x) +
      ((size_t)tile * 64 + lane) * 512 + dq * 128;
  const float* __restrict__ wb = W + (size_t)(wv * 16) * kD + dq * 512;

  float acc[16];
#pragma unroll
  for (int e = 0; e < 16; ++e) acc[e] = 0.0f;

  float4 p0 = x4[0];
  float4 p1 = x4[1];
  for (int c = 0; c < 64; ++c) {
    const float4 xa = p0;
    const float4 xb = p1;
    if (c < 63) {  // prefetch next 8-d pair; in flight during the 128 FMAs
      p0 = x4[2 * c + 2];
      p1 = x4[2 * c + 3];
    }
    const float* __restrict__ wc = wb + c * 8;
#pragma unroll
    for (int e = 0; e < 16; ++e) {
      const float* __restrict__ w = wc + e * kD;  // uniform -> s_load
      acc[e] = fmaf(xa.x, w[0], acc[e]);
      acc[e] = fmaf(xa.y, w[1], acc[e]);
      acc[e] = fmaf(xa.z, w[2], acc[e]);
      acc[e] = fmaf(xa.w, w[3], acc[e]);
      acc[e] = fmaf(xb.x, w[4], acc[e]);
      acc[e] = fmaf(xb.y, w[5], acc[e]);
      acc[e] = fmaf(xb.z, w[6], acc[e]);
      acc[e] = fmaf(xb.w, w[7], acc[e]);
    }
  }

  // epilogue: write this (dq, wave)'s 16-expert partial into token's own slots
  const size_t n = (size_t)tile * 64 + lane;
  float* __restrict__ dst = out + ((dq < 2) ? (size_t)0 : kDispatchFloats) +
                            n * 128 + (dq & 1) * 64 + wv * 16;
#pragma unroll
  for (int k = 0; k < 4; ++k)
    *reinterpret_cast<float4*>(dst + k * 4) =
        make_float4(acc[4 * k], acc[4 * k + 1], acc[4 * k + 2], acc[4 * k + 3]);
}

// ---------------------------------------------------------------------------
// Kernel 2: sum 4 partials -> logits, softmax, top-2, write outputs, losses.
// 256 blocks x 256 threads, 64 tokens/block. Reads only its own tokens' slots,
// then overwrites them -> no cross-block hazard.
__global__ __launch_bounds__(256)
void gate_kernel(float* __restrict__ out, float* __restrict__ ws) {
  __shared__ float lg[64][65];
  __shared__ int ti0[64], ti1[64];
  __shared__ float tv0[64], tv1[64], tz2[64];
  const int tid  = threadIdx.x;
  const int tile = blockIdx.x;

  float* __restrict__ outd = out + (size_t)tile * 8192;
  float* __restrict__ outc = out + kDispatchFloats + (size_t)tile * 8192;
  const float4* __restrict__ d4 = reinterpret_cast<const float4*>(outd);
  const float4* __restrict__ c4 = reinterpret_cast<const float4*>(outc);

  const int tq = tid >> 4, q = tid & 15;
#pragma unroll
  for (int k = 0; k < 4; ++k) {
    const int t = k * 16 + tq;
    const float4 a = d4[t * 32 + q];
    const float4 b = d4[t * 32 + 16 + q];
    const float4 c = c4[t * 32 + q];
    const float4 d = c4[t * 32 + 16 + q];
    lg[t][q * 4 + 0] = a.x + b.x + c.x + d.x;
    lg[t][q * 4 + 1] = a.y + b.y + c.y + d.y;
    lg[t][q * 4 + 2] = a.z + b.z + c.z + d.z;
    lg[t][q * 4 + 3] = a.w + b.w + c.w + d.w;
  }
  __syncthreads();

  if (tid < 64) {
    float v0 = -INFINITY, v1 = -INFINITY;
    int i0 = 0, i1 = 0;
    for (int e = 0; e < kE; ++e) {
      const float l = lg[tid][e];
      if (l > v0) { v1 = v0; i1 = i0; v0 = l; i0 = e; }
      else if (l > v1) { v1 = l; i1 = e; }
    }
    const float m = v0;
    float s = 0.0f;
    for (int e = 0; e < kE; ++e) s += __expf(lg[tid][e] - m);
    const float rs = 1.0f / s;
    float zexp = 0.0f;
    for (int e = 0; e < kE; ++e) zexp += __expf(__expf(lg[tid][e] - m) * rs);
    const float z = logf(zexp);
    ti0[tid] = i0; ti1[tid] = i1;
    tv0[tid] = rs;                    // exp(v0-m)*rs with v0==m
    tv1[tid] = __expf(v1 - m) * rs;
    tz2[tid] = z * z;
  }
  __syncthreads();

  // losses: thread = expert, deterministic in-block order; 256 atomics/address
  if (tid < kE) {
    float g = 0.0f, cnt = 0.0f;
    for (int t = 0; t < 64; ++t) {
      if (ti0[t] == tid) { g += tv0[t]; cnt += 1.0f; }
      if (ti1[t] == tid) { g += tv1[t]; cnt += 1.0f; }
    }
    atomicAdd(&ws[tid], g);
    atomicAdd(&ws[kE + tid], cnt);
    float z2 = tz2[tid];
    for (int off = 32; off; off >>= 1) z2 += __shfl_down(z2, off);
    if (tid == 0) atomicAdd(&ws[2 * kE], z2);
  }

  // outputs: 4 threads per token, 8 float4 per tensor each (overwrites partials)
  {
    const int t = tid >> 2, sub = tid & 3;
    const int i0 = ti0[t], i1 = ti1[t];
    const float v0 = tv0[t], v1 = tv1[t];
    float4* __restrict__ dp = reinterpret_cast<float4*>(outd) + t * 32;
    float4* __restrict__ cp = reinterpret_cast<float4*>(outc) + t * 32;
#pragma unroll
    for (int j = 0; j < 8; ++j) {
      const int qq = sub * 8 + j;
      const int e0 = qq * 2, e1 = qq * 2 + 1;
      const float d0v = (e0 == i0 || e0 == i1) ? 1.0f : 0.0f;
      const float d1v = (e1 == i0 || e1 == i1) ? 1.0f : 0.0f;
      const float c0 = (e0 == i0) ? v0 : ((e0 == i1) ? v1 : 0.0f);
      const float c1 = (e1 == i0) ? v0 : ((e1 == i1) ? v1 : 0.0f);
      dp[qq] = make_float4(d0v, 0.0f, d1v, 0.0f);
      cp[qq] = make_float4(c0, 0.0f, c1, 0.0f);
    }
  }
}

// ---------------------------------------------------------------------------
__global__ void finalize_kernel(const float* __restrict__ ws,
                                float* __restrict__ out) {
  const int e = threadIdx.x;  // 64 threads
  float prod = ws[e] * ws[kE + e];
  for (int off = 32; off; off >>= 1) prod += __shfl_down(prod, off);
  if (e == 0) {
    const size_t base = kDispatchFloats * 2;
    const float invN = 1.0f / (float)kN;
    out[base]     = prod * ((float)kE * invN * invN);  // load_balancing_loss
    out[base + 1] = ws[2 * kE] * invN;                 // router_z_loss
  }
}

// ---------------------------------------------------------------------------
extern "C" void kernel_launch(void* const* d_in, const int* in_sizes, int n_in,
                              void* d_out, int out_size, void* d_ws,
                              size_t ws_size, hipStream_t stream) {
  const float* x = (const float*)d_in[0];  // [4,4096,2048] fp32
  const float* W = (const float*)d_in[1];  // [64,2048] fp32
  float* out = (float*)d_out;
  float* ws = (float*)d_ws;

  zero_ws_kernel<<<1, 256, 0, stream>>>(ws);
  logits_kernel<<<1024, 256, 0, stream>>>(x, W, out);
  gate_kernel<<<256, 256, 0, stream>>>(out, ws);
  finalize_kernel<<<1, kE, 0, stream>>>(ws, out);
}

// Round 7
// 142.688 us; speedup vs baseline: 2.6783x; 1.0919x over previous
//
#include <hip/hip_runtime.h>
#include <hip/hip_bf16.h>
#include <cstddef>

// MoE gate: B,S,D,E,K = 4,4096,2048,64,2. N = 16384 tokens.
// out layout: dispatch [N][E][K] (2,097,152 f) | combine [N][E][K] | lbl | z
namespace {
constexpr int kD = 2048;
constexpr int kE = 64;
constexpr int kN = 16384;
constexpr size_t kDispatchFloats = (size_t)kN * kE * 2;  // 2,097,152
}

// ---------------------------------------------------------------------------
__global__ void zero_ws_kernel(float* __restrict__ ws) {
  ws[threadIdx.x] = 0.0f;  // 256 accumulator slots (129 used)
}

// ---------------------------------------------------------------------------
// Kernel 1: partial logits. Grid 1024 = 256 token-tiles x 4 d-quarters
// (tile = bid&255, dq = bid>>8 so a tile's 4 blocks share an XCD/L2).
// Block = 512 threads = 8 waves = 4 expert-groups x 2 d-halves (256 d each):
// 32 waves/CU = 100% occupancy cap (was 16/CU at 41% measured in r6 -> the
// grid was the cap; per-wave duty ~39% needs ~8 waves/SIMD to saturate VALU).
// lane = token. Inner loop: per-lane global float4 x loads (vmcnt only,
// depth-2 prefetch, statically indexed) + wave-uniform W s_loads (lgkmcnt
// only) + pure v_fma. No LDS in the hot loop; one padded-LDS exchange in the
// epilogue reduces the two d-halves.
// Partial[dq][token][e] stored inside the token's own output slots:
//   dq 0/1 -> dispatch[n*128 + dq*64 + eg*16], dq 2/3 -> combine[...]
__global__ __launch_bounds__(512)
void logits_kernel(const float* __restrict__ x, const float* __restrict__ W,
                   float* __restrict__ out) {
  __shared__ float red[4][64][17];  // dh==1 partials, padded (17 coprime 32)
  const int tid  = threadIdx.x;
  const int lane = tid & 63;
  const int wv   = __builtin_amdgcn_readfirstlane(tid >> 6);  // 0..7
  const int eg   = wv & 3;   // expert group (16 experts)
  const int dh   = wv >> 2;  // d-half within the quarter (256 floats)
  const int tile = blockIdx.x & 255;
  const int dq   = blockIdx.x >> 8;

  // x as float4: token row = 512 float4s; this wave covers 64 float4s at
  // [dq*512 + dh*256, +256) floats = [dq*128 + dh*64, +64) float4s.
  const float4* __restrict__ x4 = reinterpret_cast<const float4*>(x) +
      ((size_t)tile * 64 + lane) * 512 + dq * 128 + dh * 64;
  const float* __restrict__ wb =
      W + (size_t)(eg * 16) * kD + dq * 512 + dh * 256;

  float acc[16];
#pragma unroll
  for (int e = 0; e < 16; ++e) acc[e] = 0.0f;

  // depth-2 prefetch ring, statically indexed (runtime-indexed arrays spill)
  float4 a0 = x4[0], a1 = x4[1];   // iteration c
  float4 b0 = x4[2], b1 = x4[3];   // iteration c+1

#define FMA8(xa, xb, wptr)                                   \
  {                                                          \
    const float* __restrict__ w_ = (wptr);                   \
    _Pragma("unroll") for (int e = 0; e < 16; ++e) {         \
      const float* __restrict__ we = w_ + e * kD;            \
      acc[e] = fmaf((xa).x, we[0], acc[e]);                  \
      acc[e] = fmaf((xa).y, we[1], acc[e]);                  \
      acc[e] = fmaf((xa).z, we[2], acc[e]);                  \
      acc[e] = fmaf((xa).w, we[3], acc[e]);                  \
      acc[e] = fmaf((xb).x, we[4], acc[e]);                  \
      acc[e] = fmaf((xb).y, we[5], acc[e]);                  \
      acc[e] = fmaf((xb).z, we[6], acc[e]);                  \
      acc[e] = fmaf((xb).w, we[7], acc[e]);                  \
    }                                                        \
  }

  for (int c = 0; c < 32; c += 2) {
    const float4 xa = a0, xb = a1;
    if (c + 2 < 32) { a0 = x4[2 * c + 4]; a1 = x4[2 * c + 5]; }
    FMA8(xa, xb, wb + c * 8);
    const float4 xc = b0, xd = b1;
    if (c + 3 < 32) { b0 = x4[2 * c + 6]; b1 = x4[2 * c + 7]; }
    FMA8(xc, xd, wb + (c + 1) * 8);
  }
#undef FMA8

  // reduce the two d-halves through padded LDS (epilogue only, conflict-free)
  if (dh == 1) {
#pragma unroll
    for (int e = 0; e < 16; ++e) red[eg][lane][e] = acc[e];
  }
  __syncthreads();
  if (dh == 0) {
    float v[16];
#pragma unroll
    for (int e = 0; e < 16; ++e) v[e] = acc[e] + red[eg][lane][e];
    // write this (dq, eg) 16-expert partial into the token's own out slots
    const size_t n = (size_t)tile * 64 + lane;
    float* __restrict__ dst = out + ((dq < 2) ? (size_t)0 : kDispatchFloats) +
                              n * 128 + (dq & 1) * 64 + eg * 16;
#pragma unroll
    for (int k = 0; k < 4; ++k)
      *reinterpret_cast<float4*>(dst + k * 4) =
          make_float4(v[4 * k], v[4 * k + 1], v[4 * k + 2], v[4 * k + 3]);
  }
}

// ---------------------------------------------------------------------------
// Kernel 2: sum 4 partials -> logits, softmax, top-2, write outputs, losses.
// 256 blocks x 256 threads, 64 tokens/block. Reads only its own tokens' slots,
// then overwrites them -> no cross-block hazard.
__global__ __launch_bounds__(256)
void gate_kernel(float* __restrict__ out, float* __restrict__ ws) {
  __shared__ float lg[64][65];
  __shared__ int ti0[64], ti1[64];
  __shared__ float tv0[64], tv1[64], tz2[64];
  const int tid  = threadIdx.x;
  const int tile = blockIdx.x;

  float* __restrict__ outd = out + (size_t)tile * 8192;
  float* __restrict__ outc = out + kDispatchFloats + (size_t)tile * 8192;
  const float4* __restrict__ d4 = reinterpret_cast<const float4*>(outd);
  const float4* __restrict__ c4 = reinterpret_cast<const float4*>(outc);

  const int tq = tid >> 4, q = tid & 15;
#pragma unroll
  for (int k = 0; k < 4; ++k) {
    const int t = k * 16 + tq;
    const float4 a = d4[t * 32 + q];
    const float4 b = d4[t * 32 + 16 + q];
    const float4 c = c4[t * 32 + q];
    const float4 d = c4[t * 32 + 16 + q];
    lg[t][q * 4 + 0] = a.x + b.x + c.x + d.x;
    lg[t][q * 4 + 1] = a.y + b.y + c.y + d.y;
    lg[t][q * 4 + 2] = a.z + b.z + c.z + d.z;
    lg[t][q * 4 + 3] = a.w + b.w + c.w + d.w;
  }
  __syncthreads();

  if (tid < 64) {
    float v0 = -INFINITY, v1 = -INFINITY;
    int i0 = 0, i1 = 0;
    for (int e = 0; e < kE; ++e) {
      const float l = lg[tid][e];
      if (l > v0) { v1 = v0; i1 = i0; v0 = l; i0 = e; }
      else if (l > v1) { v1 = l; i1 = e; }
    }
    const float m = v0;
    float s = 0.0f;
    for (int e = 0; e < kE; ++e) s += __expf(lg[tid][e] - m);
    const float rs = 1.0f / s;
    float zexp = 0.0f;
    for (int e = 0; e < kE; ++e) zexp += __expf(__expf(lg[tid][e] - m) * rs);
    const float z = logf(zexp);
    ti0[tid] = i0; ti1[tid] = i1;
    tv0[tid] = rs;                    // exp(v0-m)*rs with v0==m
    tv1[tid] = __expf(v1 - m) * rs;
    tz2[tid] = z * z;
  }
  __syncthreads();

  // losses: thread = expert, deterministic in-block order; 256 atomics/address
  if (tid < kE) {
    float g = 0.0f, cnt = 0.0f;
    for (int t = 0; t < 64; ++t) {
      if (ti0[t] == tid) { g += tv0[t]; cnt += 1.0f; }
      if (ti1[t] == tid) { g += tv1[t]; cnt += 1.0f; }
    }
    atomicAdd(&ws[tid], g);
    atomicAdd(&ws[kE + tid], cnt);
    float z2 = tz2[tid];
    for (int off = 32; off; off >>= 1) z2 += __shfl_down(z2, off);
    if (tid == 0) atomicAdd(&ws[2 * kE], z2);
  }

  // outputs: 4 threads per token, 8 float4 per tensor each (overwrites partials)
  {
    const int t = tid >> 2, sub = tid & 3;
    const int i0 = ti0[t], i1 = ti1[t];
    const float v0 = tv0[t], v1 = tv1[t];
    float4* __restrict__ dp = reinterpret_cast<float4*>(outd) + t * 32;
    float4* __restrict__ cp = reinterpret_cast<float4*>(outc) + t * 32;
#pragma unroll
    for (int j = 0; j < 8; ++j) {
      const int qq = sub * 8 + j;
      const int e0 = qq * 2, e1 = qq * 2 + 1;
      const float d0v = (e0 == i0 || e0 == i1) ? 1.0f : 0.0f;
      const float d1v = (e1 == i0 || e1 == i1) ? 1.0f : 0.0f;
      const float c0 = (e0 == i0) ? v0 : ((e0 == i1) ? v1 : 0.0f);
      const float c1 = (e1 == i0) ? v0 : ((e1 == i1) ? v1 : 0.0f);
      dp[qq] = make_float4(d0v, 0.0f, d1v, 0.0f);
      cp[qq] = make_float4(c0, 0.0f, c1, 0.0f);
    }
  }
}

// ---------------------------------------------------------------------------
__global__ void finalize_kernel(const float* __restrict__ ws,
                                float* __restrict__ out) {
  const int e = threadIdx.x;  // 64 threads
  float prod = ws[e] * ws[kE + e];
  for (int off = 32; off; off >>= 1) prod += __shfl_down(prod, off);
  if (e == 0) {
    const size_t base = kDispatchFloats * 2;
    const float invN = 1.0f / (float)kN;
    out[base]     = prod * ((float)kE * invN * invN);  // load_balancing_loss
    out[base + 1] = ws[2 * kE] * invN;                 // router_z_loss
  }
}

// ---------------------------------------------------------------------------
extern "C" void kernel_launch(void* const* d_in, const int* in_sizes, int n_in,
                              void* d_out, int out_size, void* d_ws,
                              size_t ws_size, hipStream_t stream) {
  const float* x = (const float*)d_in[0];  // [4,4096,2048] fp32
  const float* W = (const float*)d_in[1];  // [64,2048] fp32
  float* out = (float*)d_out;
  float* ws = (float*)d_ws;

  zero_ws_kernel<<<1, 256, 0, stream>>>(ws);
  logits_kernel<<<1024, 512, 0, stream>>>(x, W, out);
  gate_kernel<<<256, 256, 0, stream>>>(out, ws);
  finalize_kernel<<<1, kE, 0, stream>>>(ws, out);
}

// Round 8
// 75.229 us; speedup vs baseline: 5.0799x; 1.8967x over previous
//
#include <hip/hip_runtime.h>
#include <hip/hip_bf16.h>
#include <cstddef>

// MoE gate: B,S,D,E,K = 4,4096,2048,64,2. N = 16384 tokens.
// out layout: dispatch [N][E][K] (2,097,152 f) | combine [N][E][K] | lbl | z
namespace {
constexpr int kD = 2048;
constexpr int kE = 64;
constexpr int kN = 16384;
constexpr size_t kDispatchFloats = (size_t)kN * kE * 2;  // 2,097,152
}

typedef short short8_t __attribute__((ext_vector_type(8)));
typedef float f32x4 __attribute__((ext_vector_type(4)));

// ---------------------------------------------------------------------------
__global__ void zero_ws_kernel(float* __restrict__ ws) {
  ws[threadIdx.x] = 0.0f;  // 256 accumulator slots (129 used)
}

// fp32 -> 3 scaled bf16 splits: x ~= s1 + s2*2^-8 + s3*2^-16 (all normal bf16)
__device__ __forceinline__ void split3(float f, unsigned short& s1,
                                       unsigned short& s2, unsigned short& s3) {
  __hip_bfloat16 h1 = __float2bfloat16(f);
  float r1 = (f - __bfloat162float(h1)) * 256.0f;
  __hip_bfloat16 h2 = __float2bfloat16(r1);
  float r2 = (r1 - __bfloat162float(h2)) * 256.0f;
  __hip_bfloat16 h3 = __float2bfloat16(r2);
  s1 = __builtin_bit_cast(unsigned short, h1);
  s2 = __builtin_bit_cast(unsigned short, h2);
  s3 = __builtin_bit_cast(unsigned short, h3);
}

// ---------------------------------------------------------------------------
// Kernel 1: partial logits via bf16 triple-split MFMA emulation of fp32 GEMM.
// Grid 1024 = 256 token-tiles x 4 K-quarters (512 k each); block 256 thr =
// 4 waves; wave (wr,wc) = 32-token x 32-expert quadrant. BK=64, single-buffer
// LDS 48KB, XOR-swizzled 16B cols. Exact C/D layout per m89: col=lane&15,
// row=(lane>>4)*4+reg. Partials -> token's own out slots (r6 scheme).
__global__ __launch_bounds__(256)
void logits_kernel(const float* __restrict__ x, const float* __restrict__ W,
                   float* __restrict__ out) {
  __shared__ unsigned short xs[3][64][64];   // [split][token][k]  24 KB
  __shared__ unsigned short wsh[3][64][64];  // [split][expert][k] 24 KB

  const int tid  = threadIdx.x;
  const int tile = blockIdx.x & 255;
  const int dq   = blockIdx.x >> 8;

  // staging role: 4 threads per row, 64B contiguous each (coalesced)
  const int row = tid >> 2;   // token (x) / expert (W)
  const int seg = tid & 3;    // 16-float segment within 64-k chunk
  const float4* __restrict__ bx = reinterpret_cast<const float4*>(x) +
      ((size_t)(tile * 64 + row)) * 512 + dq * 128 + seg * 4;
  const float4* __restrict__ bw = reinterpret_cast<const float4*>(W) +
      (size_t)row * 512 + dq * 128 + seg * 4;

  // compute role
  const int lane = tid & 63;
  const int wv   = __builtin_amdgcn_readfirstlane(tid >> 6);
  const int wr   = wv >> 1;        // token half (32)
  const int wc   = wv & 1;         // expert half (32)
  const int lrow = lane & 15;
  const int lk   = lane >> 4;      // k-block 0..3

  f32x4 acc0[2][2], acc1[2][2], acc2[2][2];
  const f32x4 z4 = {0.0f, 0.0f, 0.0f, 0.0f};
#pragma unroll
  for (int a = 0; a < 2; ++a)
#pragma unroll
    for (int b = 0; b < 2; ++b) { acc0[a][b] = z4; acc1[a][b] = z4; acc2[a][b] = z4; }

  for (int c = 0; c < 8; ++c) {           // 8 BK-steps of 64 k
    __syncthreads();                       // LDS free (prev compute done)
    float4 vx[4], vw[4];
#pragma unroll
    for (int j = 0; j < 4; ++j) vx[j] = bx[c * 16 + j];
#pragma unroll
    for (int j = 0; j < 4; ++j) vw[j] = bw[c * 16 + j];

    // --- convert + swizzled LDS store: x ---
    {
      short8_t o1[2], o2[2], o3[2];
#pragma unroll
      for (int j = 0; j < 4; ++j) {
        const float4 v = vx[j];
        const int ch = j >> 1, b0 = (j & 1) * 4;
        unsigned short s1, s2, s3;
        split3(v.x, s1, s2, s3); o1[ch][b0+0]=(short)s1; o2[ch][b0+0]=(short)s2; o3[ch][b0+0]=(short)s3;
        split3(v.y, s1, s2, s3); o1[ch][b0+1]=(short)s1; o2[ch][b0+1]=(short)s2; o3[ch][b0+1]=(short)s3;
        split3(v.z, s1, s2, s3); o1[ch][b0+2]=(short)s1; o2[ch][b0+2]=(short)s2; o3[ch][b0+2]=(short)s3;
        split3(v.w, s1, s2, s3); o1[ch][b0+3]=(short)s1; o2[ch][b0+3]=(short)s2; o3[ch][b0+3]=(short)s3;
      }
#pragma unroll
      for (int ch = 0; ch < 2; ++ch) {
        const int col = (seg * 2 + ch) ^ (row & 7);
        *reinterpret_cast<short8_t*>(&xs[0][row][col * 8]) = o1[ch];
        *reinterpret_cast<short8_t*>(&xs[1][row][col * 8]) = o2[ch];
        *reinterpret_cast<short8_t*>(&xs[2][row][col * 8]) = o3[ch];
      }
    }
    // --- convert + swizzled LDS store: W ---
    {
      short8_t o1[2], o2[2], o3[2];
#pragma unroll
      for (int j = 0; j < 4; ++j) {
        const float4 v = vw[j];
        const int ch = j >> 1, b0 = (j & 1) * 4;
        unsigned short s1, s2, s3;
        split3(v.x, s1, s2, s3); o1[ch][b0+0]=(short)s1; o2[ch][b0+0]=(short)s2; o3[ch][b0+0]=(short)s3;
        split3(v.y, s1, s2, s3); o1[ch][b0+1]=(short)s1; o2[ch][b0+1]=(short)s2; o3[ch][b0+1]=(short)s3;
        split3(v.z, s1, s2, s3); o1[ch][b0+2]=(short)s1; o2[ch][b0+2]=(short)s2; o3[ch][b0+2]=(short)s3;
        split3(v.w, s1, s2, s3); o1[ch][b0+3]=(short)s1; o2[ch][b0+3]=(short)s2; o3[ch][b0+3]=(short)s3;
      }
#pragma unroll
      for (int ch = 0; ch < 2; ++ch) {
        const int col = (seg * 2 + ch) ^ (row & 7);
        *reinterpret_cast<short8_t*>(&wsh[0][row][col * 8]) = o1[ch];
        *reinterpret_cast<short8_t*>(&wsh[1][row][col * 8]) = o2[ch];
        *reinterpret_cast<short8_t*>(&wsh[2][row][col * 8]) = o3[ch];
      }
    }
    __syncthreads();                       // tile ready

    // --- MFMA compute: 2 ksteps x 2 mt x 2 nt x 6 products ---
#pragma unroll
    for (int ks = 0; ks < 2; ++ks) {
      const int kc = ks * 4 + lk;          // 16B col 0..7 (pre-swizzle)
      short8_t a1[2], a2[2], a3[2], b1[2], b2[2], b3[2];
#pragma unroll
      for (int mt = 0; mt < 2; ++mt) {
        const int r = wr * 32 + mt * 16 + lrow;
        const int cw = (kc ^ (r & 7)) * 8;
        a1[mt] = *reinterpret_cast<const short8_t*>(&xs[0][r][cw]);
        a2[mt] = *reinterpret_cast<const short8_t*>(&xs[1][r][cw]);
        a3[mt] = *reinterpret_cast<const short8_t*>(&xs[2][r][cw]);
      }
#pragma unroll
      for (int nt = 0; nt < 2; ++nt) {
        const int e = wc * 32 + nt * 16 + lrow;
        const int cw = (kc ^ (e & 7)) * 8;
        b1[nt] = *reinterpret_cast<const short8_t*>(&wsh[0][e][cw]);
        b2[nt] = *reinterpret_cast<const short8_t*>(&wsh[1][e][cw]);
        b3[nt] = *reinterpret_cast<const short8_t*>(&wsh[2][e][cw]);
      }
#pragma unroll
      for (int mt = 0; mt < 2; ++mt)
#pragma unroll
        for (int nt = 0; nt < 2; ++nt) {
          acc0[mt][nt] = __builtin_amdgcn_mfma_f32_16x16x32_bf16(a1[mt], b1[nt], acc0[mt][nt], 0, 0, 0);
          acc1[mt][nt] = __builtin_amdgcn_mfma_f32_16x16x32_bf16(a1[mt], b2[nt], acc1[mt][nt], 0, 0, 0);
          acc1[mt][nt] = __builtin_amdgcn_mfma_f32_16x16x32_bf16(a2[mt], b1[nt], acc1[mt][nt], 0, 0, 0);
          acc2[mt][nt] = __builtin_amdgcn_mfma_f32_16x16x32_bf16(a1[mt], b3[nt], acc2[mt][nt], 0, 0, 0);
          acc2[mt][nt] = __builtin_amdgcn_mfma_f32_16x16x32_bf16(a3[mt], b1[nt], acc2[mt][nt], 0, 0, 0);
          acc2[mt][nt] = __builtin_amdgcn_mfma_f32_16x16x32_bf16(a2[mt], b2[nt], acc2[mt][nt], 0, 0, 0);
        }
    }
  }

  // epilogue: L = acc0 + acc1*2^-8 + acc2*2^-16 -> token's own partial slots
  const float k8 = 1.0f / 256.0f, k16 = 1.0f / 65536.0f;
  float* __restrict__ base = out + ((dq < 2) ? (size_t)0 : kDispatchFloats);
#pragma unroll
  for (int mt = 0; mt < 2; ++mt)
#pragma unroll
    for (int r = 0; r < 4; ++r) {
      const int trow = wr * 32 + mt * 16 + lk * 4 + r;  // C row = (lane>>4)*4+r
      const size_t n = (size_t)tile * 64 + trow;
      float* __restrict__ dst =
          base + n * 128 + (dq & 1) * 64 + wc * 32 + lrow;  // C col = lane&15
#pragma unroll
      for (int nt = 0; nt < 2; ++nt) {
        dst[nt * 16] = acc0[mt][nt][r] + acc1[mt][nt][r] * k8 + acc2[mt][nt][r] * k16;
      }
    }
}

// ---------------------------------------------------------------------------
// Kernel 2: sum 4 partials -> logits, softmax, top-2, write outputs, losses.
__global__ __launch_bounds__(256)
void gate_kernel(float* __restrict__ out, float* __restrict__ ws) {
  __shared__ float lg[64][65];
  __shared__ int ti0[64], ti1[64];
  __shared__ float tv0[64], tv1[64], tz2[64];
  const int tid  = threadIdx.x;
  const int tile = blockIdx.x;

  float* __restrict__ outd = out + (size_t)tile * 8192;
  float* __restrict__ outc = out + kDispatchFloats + (size_t)tile * 8192;
  const float4* __restrict__ d4 = reinterpret_cast<const float4*>(outd);
  const float4* __restrict__ c4 = reinterpret_cast<const float4*>(outc);

  const int tq = tid >> 4, q = tid & 15;
#pragma unroll
  for (int k = 0; k < 4; ++k) {
    const int t = k * 16 + tq;
    const float4 a = d4[t * 32 + q];
    const float4 b = d4[t * 32 + 16 + q];
    const float4 c = c4[t * 32 + q];
    const float4 d = c4[t * 32 + 16 + q];
    lg[t][q * 4 + 0] = a.x + b.x + c.x + d.x;
    lg[t][q * 4 + 1] = a.y + b.y + c.y + d.y;
    lg[t][q * 4 + 2] = a.z + b.z + c.z + d.z;
    lg[t][q * 4 + 3] = a.w + b.w + c.w + d.w;
  }
  __syncthreads();

  if (tid < 64) {
    float v0 = -INFINITY, v1 = -INFINITY;
    int i0 = 0, i1 = 0;
    for (int e = 0; e < kE; ++e) {
      const float l = lg[tid][e];
      if (l > v0) { v1 = v0; i1 = i0; v0 = l; i0 = e; }
      else if (l > v1) { v1 = l; i1 = e; }
    }
    const float m = v0;
    float s = 0.0f;
    for (int e = 0; e < kE; ++e) s += __expf(lg[tid][e] - m);
    const float rs = 1.0f / s;
    float zexp = 0.0f;
    for (int e = 0; e < kE; ++e) zexp += __expf(__expf(lg[tid][e] - m) * rs);
    const float z = logf(zexp);
    ti0[tid] = i0; ti1[tid] = i1;
    tv0[tid] = rs;                    // exp(v0-m)*rs with v0==m
    tv1[tid] = __expf(v1 - m) * rs;
    tz2[tid] = z * z;
  }
  __syncthreads();

  if (tid < kE) {
    float g = 0.0f, cnt = 0.0f;
    for (int t = 0; t < 64; ++t) {
      if (ti0[t] == tid) { g += tv0[t]; cnt += 1.0f; }
      if (ti1[t] == tid) { g += tv1[t]; cnt += 1.0f; }
    }
    atomicAdd(&ws[tid], g);
    atomicAdd(&ws[kE + tid], cnt);
    float z2 = tz2[tid];
    for (int off = 32; off; off >>= 1) z2 += __shfl_down(z2, off);
    if (tid == 0) atomicAdd(&ws[2 * kE], z2);
  }

  {
    const int t = tid >> 2, sub = tid & 3;
    const int i0 = ti0[t], i1 = ti1[t];
    const float v0 = tv0[t], v1 = tv1[t];
    float4* __restrict__ dp = reinterpret_cast<float4*>(outd) + t * 32;
    float4* __restrict__ cp = reinterpret_cast<float4*>(outc) + t * 32;
#pragma unroll
    for (int j = 0; j < 8; ++j) {
      const int qq = sub * 8 + j;
      const int e0 = qq * 2, e1 = qq * 2 + 1;
      const float d0v = (e0 == i0 || e0 == i1) ? 1.0f : 0.0f;
      const float d1v = (e1 == i0 || e1 == i1) ? 1.0f : 0.0f;
      const float c0 = (e0 == i0) ? v0 : ((e0 == i1) ? v1 : 0.0f);
      const float c1 = (e1 == i0) ? v0 : ((e1 == i1) ? v1 : 0.0f);
      dp[qq] = make_float4(d0v, 0.0f, d1v, 0.0f);
      cp[qq] = make_float4(c0, 0.0f, c1, 0.0f);
    }
  }
}

// ---------------------------------------------------------------------------
__global__ void finalize_kernel(const float* __restrict__ ws,
                                float* __restrict__ out) {
  const int e = threadIdx.x;  // 64 threads
  float prod = ws[e] * ws[kE + e];
  for (int off = 32; off; off >>= 1) prod += __shfl_down(prod, off);
  if (e == 0) {
    const size_t base = kDispatchFloats * 2;
    const float invN = 1.0f / (float)kN;
    out[base]     = prod * ((float)kE * invN * invN);  // load_balancing_loss
    out[base + 1] = ws[2 * kE] * invN;                 // router_z_loss
  }
}

// ---------------------------------------------------------------------------
extern "C" void kernel_launch(void* const* d_in, const int* in_sizes, int n_in,
                              void* d_out, int out_size, void* d_ws,
                              size_t ws_size, hipStream_t stream) {
  const float* x = (const float*)d_in[0];  // [4,4096,2048] fp32
  const float* W = (const float*)d_in[1];  // [64,2048] fp32
  float* out = (float*)d_out;
  float* ws = (float*)d_ws;

  zero_ws_kernel<<<1, 256, 0, stream>>>(ws);
  logits_kernel<<<1024, 256, 0, stream>>>(x, W, out);
  gate_kernel<<<256, 256, 0, stream>>>(out, ws);
  finalize_kernel<<<1, kE, 0, stream>>>(ws, out);
}